// Round 1
// baseline (197.093 us; speedup 1.0000x reference)
//
#include <hip/hip_runtime.h>
#include <hip/hip_fp16.h>

#define N_NODES 8192
#define F_IN    512
#define F_OUT   256
#define LOG2E   1.4426950408889634f

typedef __attribute__((ext_vector_type(8))) _Float16 half8;
typedef __attribute__((ext_vector_type(2))) __fp16   fp16x2;
typedef __attribute__((ext_vector_type(4))) float    f32x4;
typedef __attribute__((ext_vector_type(4))) int      i32x4;

union H8U4 { half8 h; uint4 u; };
union H2U  { fp16x2 h; unsigned u; };

// ---------------------------------------------------------------------------
// k_init: replaces the 4-byte hipMemsetAsync (an in-graph 4B fill cost ~155us).
// ---------------------------------------------------------------------------
__global__ void k_init(unsigned* __restrict__ emax_u) {
  if (threadIdx.x == 0 && blockIdx.x == 0) *emax_u = 0u;
}

// ---------------------------------------------------------------------------
// k_hgemm (verified r5/r6, unchanged this round): h = x@W in f32 regs; pack h
// into 16x16x32-f16 B-fragment layout; fused e-dots; per-block max -> atomic.
// ---------------------------------------------------------------------------
__global__ __launch_bounds__(512) void k_hgemm(const float* __restrict__ x,
                                               const float* __restrict__ W,
                                               const float* __restrict__ a,
                                               unsigned short* __restrict__ hpack,
                                               float* __restrict__ EI,
                                               float* __restrict__ EJ,
                                               unsigned* __restrict__ emax_u) {
  __shared__ __align__(16) float xs[32 * 128];
  __shared__ float emx[32];
  const int r0  = blockIdx.x * 32;
  const int tid = threadIdx.x;
  const int cg  = tid & 31;       // col group -> 8 cols
  const int rg  = tid >> 5;       // 0..15 -> 2 rows
  const int c0  = cg * 8;
  float acc[2][8];
#pragma unroll
  for (int r = 0; r < 2; ++r)
#pragma unroll
    for (int i = 0; i < 8; ++i) acc[r][i] = 0.f;

  for (int kc = 0; kc < 4; ++kc) {
    __syncthreads();
#pragma unroll
    for (int i = 0; i < 2; ++i) {
      const int idx = tid + i * 512;           // float4 index, 1024 total
      const int row = idx >> 5;                // 0..31
      const int cc  = (idx & 31) * 4;
      *(float4*)&xs[row * 128 + cc] =
          *(const float4*)&x[(size_t)(r0 + row) * F_IN + kc * 128 + cc];
    }
    __syncthreads();
    const float* xr0 = &xs[(rg * 2 + 0) * 128];
    const float* xr1 = &xs[(rg * 2 + 1) * 128];
    const float* wp  = W + (size_t)(kc * 128) * F_OUT + c0;
    for (int k2 = 0; k2 < 128; ++k2) {
      const float4 w0 = *(const float4*)(wp);
      const float4 w1 = *(const float4*)(wp + 4);
      wp += F_OUT;
      const float xa = xr0[k2], xb = xr1[k2];
      acc[0][0] = fmaf(xa, w0.x, acc[0][0]);
      acc[0][1] = fmaf(xa, w0.y, acc[0][1]);
      acc[0][2] = fmaf(xa, w0.z, acc[0][2]);
      acc[0][3] = fmaf(xa, w0.w, acc[0][3]);
      acc[0][4] = fmaf(xa, w1.x, acc[0][4]);
      acc[0][5] = fmaf(xa, w1.y, acc[0][5]);
      acc[0][6] = fmaf(xa, w1.z, acc[0][6]);
      acc[0][7] = fmaf(xa, w1.w, acc[0][7]);
      acc[1][0] = fmaf(xb, w0.x, acc[1][0]);
      acc[1][1] = fmaf(xb, w0.y, acc[1][1]);
      acc[1][2] = fmaf(xb, w0.z, acc[1][2]);
      acc[1][3] = fmaf(xb, w0.w, acc[1][3]);
      acc[1][4] = fmaf(xb, w1.x, acc[1][4]);
      acc[1][5] = fmaf(xb, w1.y, acc[1][5]);
      acc[1][6] = fmaf(xb, w1.z, acc[1][6]);
      acc[1][7] = fmaf(xb, w1.w, acc[1][7]);
    }
  }

  // Fused e-epilogue: per-row dots with a_src/a_dst, 32-lane shuffle reduce.
  const float4 as0 = *(const float4*)(a + c0);
  const float4 as1 = *(const float4*)(a + c0 + 4);
  const float4 ad0 = *(const float4*)(a + F_OUT + c0);
  const float4 ad1 = *(const float4*)(a + F_OUT + c0 + 4);
#pragma unroll
  for (int ri = 0; ri < 2; ++ri) {
    float s1 = acc[ri][0] * as0.x + acc[ri][1] * as0.y + acc[ri][2] * as0.z +
               acc[ri][3] * as0.w + acc[ri][4] * as1.x + acc[ri][5] * as1.y +
               acc[ri][6] * as1.z + acc[ri][7] * as1.w;
    float s2 = acc[ri][0] * ad0.x + acc[ri][1] * ad0.y + acc[ri][2] * ad0.z +
               acc[ri][3] * ad0.w + acc[ri][4] * ad1.x + acc[ri][5] * ad1.y +
               acc[ri][6] * ad1.z + acc[ri][7] * ad1.w;
#pragma unroll
    for (int o = 1; o < 32; o <<= 1) {
      s1 += __shfl_xor(s1, o);
      s2 += __shfl_xor(s2, o);
    }
    if (cg == 0) {
      const int row = r0 + rg * 2 + ri;
      EI[row] = s1 * LOG2E;
      const float e2 = s2 * LOG2E;
      EJ[row] = e2;
      emx[rg * 2 + ri] = e2;
    }
  }

  // hpack scatter stores.
#pragma unroll
  for (int ri = 0; ri < 2; ++ri) {
    const int row = r0 + rg * 2 + ri;
    const int kb = row >> 5, e = row & 7, hh = (row >> 3) & 3;
#pragma unroll
    for (int i = 0; i < 8; ++i) {
      const int col = c0 + i;
      const size_t idx =
          (((size_t)kb * 16 + (col >> 4)) * 64 + (col & 15) + 16 * hh) * 8 + e;
      _Float16 hv = (_Float16)acc[ri][i];
      hpack[idx] = *(unsigned short*)&hv;
    }
  }

  __syncthreads();
  if (tid == 0) {
    float m = emx[0];
#pragma unroll
    for (int i = 1; i < 32; ++i) m = fmaxf(m, emx[i]);
    unsigned b = __float_as_uint(m);
    unsigned u = (b & 0x80000000u) ? ~b : (b | 0x80000000u);
    atomicMax(emax_u, u);
  }
}

// ---------------------------------------------------------------------------
// k_pv r8: ONE barrier per tile via double-buffered P tile (2 x 8 KB).
// Region t (between barriers): read A-frags of tile t (latency hidden under
// P-compute), compute+write P(t+1) into the other buffer, MFMA(t), issue
// hb(t+1) global loads BEFORE the barrier so their L2/L3 latency hides under
// barrier-wait + P(t+2). Math identical to r7 (nt-adj, depth-2 adj prefetch,
// fused masked-softmax, f16 16x16x32 MFMA). Prev structure had 2 barriers per
// tile forcing lockstep P-phase/MFMA-phase; this lets them overlap per-wave.
// ---------------------------------------------------------------------------
__global__ __launch_bounds__(512, 4) void k_pv(const int* __restrict__ adj,
                                               const uint4* __restrict__ hp4,
                                               const float* __restrict__ EI,
                                               const float* __restrict__ EJ,
                                               const unsigned* __restrict__ emax_u,
                                               float* __restrict__ npart,
                                               float* __restrict__ dpart,
                                               int ntiles) {
  __shared__ __align__(16) uint4 ps4[2 * 8 * 64];  // 16 KB double-buffered P tile
  __shared__ float ejhi[2048], ejlo[2048];         // split's EJ, 0.2*EJ
  __shared__ float A1[64], A2[64], den[64];
  const int rowbase = blockIdx.x * 64;
  const int split   = blockIdx.y;
  const int jt0     = split * ntiles;
  const int tid     = threadIdx.x;
  const int wid  = tid >> 6, lane = tid & 63;
  const int lo   = lane & 15, hi = lane >> 4;

  float EMAX;
  {
    const unsigned u = *emax_u;
    EMAX = (u & 0x80000000u) ? __uint_as_float(u & 0x7fffffffu) : __uint_as_float(~u);
  }
  if (tid < 64) {
    const float e  = EI[rowbase + tid];
    const float s  = e + EMAX;
    const float mi = fmaxf(s, 0.2f * s);
    A1[tid] = e - mi;
    A2[tid] = 0.2f * e - mi;
    den[tid] = 0.f;
  }
  const bool uselds = (ntiles <= 32);
  if (uselds) {
    int eidx = jt0 * 64 + tid * 4;              // clamp guard (no-op at nsplit=4)
    if (eidx > N_NODES - 4) eidx = N_NODES - 4;
    const float4 ev = *(const float4*)&EJ[eidx];
    *(float4*)&ejhi[tid * 4] = ev;
    float4 el = {0.2f * ev.x, 0.2f * ev.y, 0.2f * ev.z, 0.2f * ev.w};
    *(float4*)&ejlo[tid * 4] = el;
  }
  __syncthreads();

  // P-writer role: slot wid = ksw*4 + msub.
  const int msub = wid & 3, ksw = wid >> 2;
  const int row_p = msub * 16 + lo;
  const int jloc  = ksw * 32 + hi * 8;
  const float a1r = A1[row_p], a2r = A2[row_p];
  const int*   adjp = adj + (size_t)(rowbase + row_p) * N_NODES + jt0 * 64 + jloc;
  const float* ejg  = EJ + jt0 * 64 + jloc;
  // MFMA-reader role: wave (mg,ng) owns rows [mg*32,+32) x cols [ng*64,+64).
  const int mg = wid >> 2, ng = wid & 3;
  const uint4* hb = hp4 + (ng * 4) * 64 + lane;

  f32x4 acc[2][4] = {};
  float dacc = 0.f;

  // compute P(jn) from adj regs + write into buffer (jn & 1)
  auto computeP = [&](int jn, i32x4 c0v, i32x4 c1v) {
    float eh[8], el[8];
    if (uselds) {
      const float4 h0 = *(const float4*)&ejhi[jn * 64 + jloc];
      const float4 h1 = *(const float4*)&ejhi[jn * 64 + jloc + 4];
      const float4 l0 = *(const float4*)&ejlo[jn * 64 + jloc];
      const float4 l1 = *(const float4*)&ejlo[jn * 64 + jloc + 4];
      eh[0]=h0.x; eh[1]=h0.y; eh[2]=h0.z; eh[3]=h0.w;
      eh[4]=h1.x; eh[5]=h1.y; eh[6]=h1.z; eh[7]=h1.w;
      el[0]=l0.x; el[1]=l0.y; el[2]=l0.z; el[3]=l0.w;
      el[4]=l1.x; el[5]=l1.y; el[6]=l1.z; el[7]=l1.w;
    } else {
      const float4 e0 = *(const float4*)(ejg + jn * 64);
      const float4 e1 = *(const float4*)(ejg + jn * 64 + 4);
      eh[0]=e0.x; eh[1]=e0.y; eh[2]=e0.z; eh[3]=e0.w;
      eh[4]=e1.x; eh[5]=e1.y; eh[6]=e1.z; eh[7]=e1.w;
#pragma unroll
      for (int j = 0; j < 8; ++j) el[j] = 0.2f * eh[j];
    }
    const int am[8] = {c0v.x, c0v.y, c0v.z, c0v.w, c1v.x, c1v.y, c1v.z, c1v.w};
    float ph[8];
#pragma unroll
    for (int j = 0; j < 8; ++j) {
      const float s = fmaxf(eh[j] + a1r, el[j] + a2r);
      const float p = __builtin_amdgcn_exp2f(s);
      ph[j] = (am[j] > 0) ? p : 0.f;
    }
    dacc += ((ph[0] + ph[1]) + (ph[2] + ph[3])) + ((ph[4] + ph[5]) + (ph[6] + ph[7]));
    H2U q0, q1, q2, q3;
    q0.h = __builtin_amdgcn_cvt_pkrtz(ph[0], ph[1]);
    q1.h = __builtin_amdgcn_cvt_pkrtz(ph[2], ph[3]);
    q2.h = __builtin_amdgcn_cvt_pkrtz(ph[4], ph[5]);
    q3.h = __builtin_amdgcn_cvt_pkrtz(ph[6], ph[7]);
    uint4 pk = {q0.u, q1.u, q2.u, q3.u};
    ps4[(jn & 1) * 512 + wid * 64 + lane] = pk;
  };

  // ---- prologue: hb(0) in flight, P(0) written, adj depth-2 primed ----
  uint4 b00, b01, b02, b03, b10, b11, b12, b13;
  {
    const int tb = jt0 * 2048;
    b00 = hb[tb + 0 * 1024 + 0 * 64];
    b01 = hb[tb + 0 * 1024 + 1 * 64];
    b02 = hb[tb + 0 * 1024 + 2 * 64];
    b03 = hb[tb + 0 * 1024 + 3 * 64];
    b10 = hb[tb + 1 * 1024 + 0 * 64];
    b11 = hb[tb + 1 * 1024 + 1 * 64];
    b12 = hb[tb + 1 * 1024 + 2 * 64];
    b13 = hb[tb + 1 * 1024 + 3 * 64];
  }
  i32x4 cur0 = __builtin_nontemporal_load((const i32x4*)(adjp));
  i32x4 cur1 = __builtin_nontemporal_load((const i32x4*)(adjp + 4));
  i32x4 nxt0 = {0, 0, 0, 0}, nxt1 = {0, 0, 0, 0};
  if (ntiles > 1) {
    nxt0 = __builtin_nontemporal_load((const i32x4*)(adjp + 64));
    nxt1 = __builtin_nontemporal_load((const i32x4*)(adjp + 68));
  }
  computeP(0, cur0, cur1);
  cur0 = nxt0; cur1 = nxt1;
  if (2 < ntiles) {
    nxt0 = __builtin_nontemporal_load((const i32x4*)(adjp + 128));
    nxt1 = __builtin_nontemporal_load((const i32x4*)(adjp + 132));
  }
  asm volatile("" ::: "memory");
  asm volatile("s_waitcnt lgkmcnt(0)" ::: "memory");  // P(0) write visible
  __builtin_amdgcn_s_barrier();
  asm volatile("" ::: "memory");

  // ---- main loop: ONE barrier per tile ----
  for (int jt = 0; jt < ntiles; ++jt) {
    // A-fragments of tile jt (buffer jt&1, written last region) — issue first,
    // latency hides under the P(jt+1) compute below.
    H8U4 a00, a10, a01, a11;
    const int cb = (jt & 1) * 512;
    a00.u = ps4[cb + (0 * 4 + mg * 2 + 0) * 64 + lane];
    a10.u = ps4[cb + (0 * 4 + mg * 2 + 1) * 64 + lane];
    a01.u = ps4[cb + (1 * 4 + mg * 2 + 0) * 64 + lane];
    a11.u = ps4[cb + (1 * 4 + mg * 2 + 1) * 64 + lane];

    // P(jt+1) into the other buffer; rotate depth-2 adj prefetch.
    if (jt + 1 < ntiles) {
      computeP(jt + 1, cur0, cur1);
      cur0 = nxt0; cur1 = nxt1;
      if (jt + 3 < ntiles) {
        const int* ap = adjp + (jt + 3) * 64;
        nxt0 = __builtin_nontemporal_load((const i32x4*)ap);
        nxt1 = __builtin_nontemporal_load((const i32x4*)(ap + 4));
      }
    }

    // MFMA(jt) — compiler's lgkmcnt before first mfma covers the a-frag reads
    // (and, in-order, the P write above).
    H8U4 b;
    __builtin_amdgcn_s_setprio(1);
    b.u = b00;
    acc[0][0] = __builtin_amdgcn_mfma_f32_16x16x32_f16(a00.h, b.h, acc[0][0], 0, 0, 0);
    acc[1][0] = __builtin_amdgcn_mfma_f32_16x16x32_f16(a10.h, b.h, acc[1][0], 0, 0, 0);
    b.u = b01;
    acc[0][1] = __builtin_amdgcn_mfma_f32_16x16x32_f16(a00.h, b.h, acc[0][1], 0, 0, 0);
    acc[1][1] = __builtin_amdgcn_mfma_f32_16x16x32_f16(a10.h, b.h, acc[1][1], 0, 0, 0);
    b.u = b02;
    acc[0][2] = __builtin_amdgcn_mfma_f32_16x16x32_f16(a00.h, b.h, acc[0][2], 0, 0, 0);
    acc[1][2] = __builtin_amdgcn_mfma_f32_16x16x32_f16(a10.h, b.h, acc[1][2], 0, 0, 0);
    b.u = b03;
    acc[0][3] = __builtin_amdgcn_mfma_f32_16x16x32_f16(a00.h, b.h, acc[0][3], 0, 0, 0);
    acc[1][3] = __builtin_amdgcn_mfma_f32_16x16x32_f16(a10.h, b.h, acc[1][3], 0, 0, 0);
    b.u = b10;
    acc[0][0] = __builtin_amdgcn_mfma_f32_16x16x32_f16(a01.h, b.h, acc[0][0], 0, 0, 0);
    acc[1][0] = __builtin_amdgcn_mfma_f32_16x16x32_f16(a11.h, b.h, acc[1][0], 0, 0, 0);
    b.u = b11;
    acc[0][1] = __builtin_amdgcn_mfma_f32_16x16x32_f16(a01.h, b.h, acc[0][1], 0, 0, 0);
    acc[1][1] = __builtin_amdgcn_mfma_f32_16x16x32_f16(a11.h, b.h, acc[1][1], 0, 0, 0);
    b.u = b12;
    acc[0][2] = __builtin_amdgcn_mfma_f32_16x16x32_f16(a01.h, b.h, acc[0][2], 0, 0, 0);
    acc[1][2] = __builtin_amdgcn_mfma_f32_16x16x32_f16(a11.h, b.h, acc[1][2], 0, 0, 0);
    b.u = b13;
    acc[0][3] = __builtin_amdgcn_mfma_f32_16x16x32_f16(a01.h, b.h, acc[0][3], 0, 0, 0);
    acc[1][3] = __builtin_amdgcn_mfma_f32_16x16x32_f16(a11.h, b.h, acc[1][3], 0, 0, 0);
    __builtin_amdgcn_s_setprio(0);

    // hb(jt+1) issued BEFORE the barrier: stays in flight across it, latency
    // hides under barrier-wait + next region's P compute.
    if (jt + 1 < ntiles) {
      const int tb = (jt0 + jt + 1) * 2048;
      b00 = hb[tb + 0 * 1024 + 0 * 64];
      b01 = hb[tb + 0 * 1024 + 1 * 64];
      b02 = hb[tb + 0 * 1024 + 2 * 64];
      b03 = hb[tb + 0 * 1024 + 3 * 64];
      b10 = hb[tb + 1 * 1024 + 0 * 64];
      b11 = hb[tb + 1 * 1024 + 1 * 64];
      b12 = hb[tb + 1 * 1024 + 2 * 64];
      b13 = hb[tb + 1 * 1024 + 3 * 64];
      asm volatile("" ::: "memory");
      asm volatile("s_waitcnt lgkmcnt(0)" ::: "memory");  // my P(jt+1) write visible
      __builtin_amdgcn_s_barrier();                       // region boundary
      asm volatile("" ::: "memory");
    }
  }

  atomicAdd(&den[row_p], dacc);
  __syncthreads();

  float* npb = npart + (size_t)split * N_NODES * F_OUT;
#pragma unroll
  for (int mi_ = 0; mi_ < 2; ++mi_) {
    const int rb = rowbase + (mg * 2 + mi_) * 16 + hi * 4;
#pragma unroll
    for (int nf = 0; nf < 4; ++nf) {
      const int col = ng * 64 + nf * 16 + lo;
#pragma unroll
      for (int r2 = 0; r2 < 4; ++r2)
        __builtin_nontemporal_store(acc[mi_][nf][r2],
                                    &npb[(size_t)(rb + r2) * F_OUT + col]);
    }
  }
  if (tid < 64)
    __builtin_nontemporal_store(den[tid],
                                &dpart[(size_t)split * N_NODES + rowbase + tid]);
}

// ---------------------------------------------------------------------------
// k_fin: combine splits, divide by denom, ELU, write output.
// ---------------------------------------------------------------------------
__global__ __launch_bounds__(256) void k_fin(const float* __restrict__ npart,
                                             const float* __restrict__ dpart,
                                             float* __restrict__ out,
                                             int nsplit) {
  const int gid = blockIdx.x * 256 + threadIdx.x;
  const int row = gid >> 6;
  const int c4  = (gid & 63) << 2;
  f32x4 s = {0.f, 0.f, 0.f, 0.f};
  float d = 0.f;
  for (int sp = 0; sp < nsplit; ++sp) {
    const f32x4 v = __builtin_nontemporal_load(
        (const f32x4*)(npart + ((size_t)sp * N_NODES + row) * F_OUT + c4));
    s += v;
    d += dpart[(size_t)sp * N_NODES + row];
  }
  const float inv = 1.f / d;
  float o[4] = {s.x * inv, s.y * inv, s.z * inv, s.w * inv};
#pragma unroll
  for (int i = 0; i < 4; ++i) o[i] = (o[i] > 0.f) ? o[i] : expm1f(o[i]);
  float4 ov = {o[0], o[1], o[2], o[3]};
  *(float4*)(out + (size_t)row * F_OUT + c4) = ov;
}

// ---------------------------------------------------------------------------
extern "C" void kernel_launch(void* const* d_in, const int* in_sizes, int n_in,
                              void* d_out, int out_size, void* d_ws, size_t ws_size,
                              hipStream_t stream) {
  const float* x   = (const float*)d_in[0];
  const int*   adj = (const int*)d_in[1];
  const float* W   = (const float*)d_in[2];
  const float* a   = (const float*)d_in[3];
  float* out = (float*)d_out;
  char*  ws  = (char*)d_ws;

  unsigned short* hpack = (unsigned short*)ws;  // 4 MB, B-fragment layout
  size_t off = (size_t)4 * 1024 * 1024;
  float* EI = (float*)(ws + off); off += (size_t)N_NODES * 4;
  float* EJ = (float*)(ws + off); off += (size_t)N_NODES * 4;
  unsigned* emax_u = (unsigned*)(ws + off); off += 256;
  float* dpart = (float*)(ws + off); off += (size_t)8 * N_NODES * 4;
  float* npart = (float*)(ws + off);

  int nsplit = 4;   // 512 blocks: all co-resident in one dispatch round (r6 lesson)
  while (nsplit > 1 && off + (size_t)nsplit * N_NODES * F_OUT * 4 > ws_size) nsplit >>= 1;

  k_init<<<dim3(1), dim3(64), 0, stream>>>(emax_u);
  k_hgemm<<<dim3(N_NODES / 32), dim3(512), 0, stream>>>(x, W, a, hpack, EI, EJ, emax_u);
  k_pv<<<dim3(128, nsplit), dim3(512), 0, stream>>>(adj, (const uint4*)hpack, EI, EJ,
                                                    emax_u, npart, dpart, 128 / nsplit);
  k_fin<<<dim3(N_NODES * 64 / 256), dim3(256), 0, stream>>>(npart, dpart, out, nsplit);
}

// Round 2
// 148.743 us; speedup vs baseline: 1.3251x; 1.3251x over previous
//
#include <hip/hip_runtime.h>
#include <hip/hip_fp16.h>

#define N_NODES 8192
#define F_IN    512
#define F_OUT   256
#define LOG2E   1.4426950408889634f

typedef __attribute__((ext_vector_type(8))) _Float16 half8;
typedef __attribute__((ext_vector_type(2))) __fp16   fp16x2;
typedef __attribute__((ext_vector_type(4))) float    f32x4;
typedef __attribute__((ext_vector_type(4))) int      i32x4;

union H8U4 { half8 h; uint4 u; };
union H2U  { fp16x2 h; unsigned u; };

// ---------------------------------------------------------------------------
// k_prep: (a) init emax; (b) pack W into f16 hi/lo B-fragment layout
// (same layout as hpack) so k_hgemm can consume W straight into MFMA B-frags.
// hi = f16(w), lo = f16(w - hi): 3-term f16 MFMA emulates fp32 GEMM to ~2^-20.
// ---------------------------------------------------------------------------
__global__ __launch_bounds__(256) void k_prep(const float* __restrict__ W,
                                              unsigned short* __restrict__ wph,
                                              unsigned short* __restrict__ wpl,
                                              unsigned* __restrict__ emax_u) {
  const int gid = blockIdx.x * 256 + threadIdx.x;   // 512 blocks -> 131072
  if (gid == 0) *emax_u = 0u;
  const int k = gid >> 8;          // 0..511
  const int c = gid & 255;         // 0..255
  const float w = W[(size_t)k * F_OUT + c];
  const _Float16 hi = (_Float16)w;
  const _Float16 lo = (_Float16)(w - (float)hi);
  const size_t idx =
      (((size_t)(k >> 5) * 16 + (c >> 4)) * 64 + (c & 15) + 16 * ((k >> 3) & 3)) * 8 +
      (k & 7);
  wph[idx] = *(const unsigned short*)&hi;
  wpl[idx] = *(const unsigned short*)&lo;
}

// ---------------------------------------------------------------------------
// k_hgemm r9: h = x@W via split-f16 MFMA (x_hi*W_hi + x_hi*W_lo + x_lo*W_hi,
// f32 accumulate; error ~2^-20 << f16 hpack quantum). Barrier-free: each wave
// loads its own x fragment from global, converts in-register; W comes from
// k_prep's packed B-frag buffers (L2-hot, 512KB). Fragment layouts mirror
// k_pv's proven conventions (A: row=l&15,k=(l>>4)*8+j; B: k=(l>>4)*8+j,
// col=l&15; C: col=l&15,row=(l>>4)*4+q). Fused e-dot epilogue + hpack scatter
// (hpack layout unchanged -> k_pv untouched). Replaces the fp32-VALU version
// that sat at its 13.6us FMA-issue floor; MFMA floor here is ~3.1us.
// ---------------------------------------------------------------------------
__global__ __launch_bounds__(512) void k_hgemm(const float* __restrict__ x,
                                               const uint4* __restrict__ wph4,
                                               const uint4* __restrict__ wpl4,
                                               const float* __restrict__ a,
                                               unsigned short* __restrict__ hpack,
                                               float* __restrict__ EI,
                                               float* __restrict__ EJ,
                                               unsigned* __restrict__ emax_u) {
  __shared__ float eip[4][32], ejp[4][32], emx[32];
  const int r0   = blockIdx.x * 32;
  const int tid  = threadIdx.x;
  const int wid  = tid >> 6, lane = tid & 63;
  const int mg   = wid >> 2, ng = wid & 3;      // 2 row-groups x 4 col-groups
  const int lo16 = lane & 15, hi4 = lane >> 4;

  // Per-lane x source: row r0+mg*16+(l&15), k-base (l>>4)*8 (A-frag layout).
  const float* xrow = x + (size_t)(r0 + mg * 16 + lo16) * F_IN + hi4 * 8;
  const uint4* whb = wph4 + (size_t)(ng * 4) * 64 + lane;  // + (ks*16+nf)*64
  const uint4* wlb = wpl4 + (size_t)(ng * 4) * 64 + lane;

  f32x4 acc[4] = {};

  float4 xa = *(const float4*)(xrow);
  float4 xb = *(const float4*)(xrow + 4);
  uint4 wh[4], wl[4];
#pragma unroll
  for (int nf = 0; nf < 4; ++nf) {
    wh[nf] = whb[(size_t)nf * 64];
    wl[nf] = wlb[(size_t)nf * 64];
  }

#pragma unroll
  for (int ks = 0; ks < 16; ++ks) {
    // Convert current x chunk to f16 hi/lo fragments.
    H8U4 ah, al;
    const float v[8] = {xa.x, xa.y, xa.z, xa.w, xb.x, xb.y, xb.z, xb.w};
#pragma unroll
    for (int j = 0; j < 8; ++j) {
      const _Float16 h = (_Float16)v[j];
      ah.h[j] = h;
      al.h[j] = (_Float16)(v[j] - (float)h);
    }
    // Prefetch next x chunk (latency hides under MFMAs below).
    if (ks + 1 < 16) {
      xa = *(const float4*)(xrow + (ks + 1) * 32);
      xb = *(const float4*)(xrow + (ks + 1) * 32 + 4);
    }
    // 12 MFMAs: 3 precision terms x 4 col-fragments.
#pragma unroll
    for (int nf = 0; nf < 4; ++nf) {
      H8U4 bh, bl;
      bh.u = wh[nf];
      bl.u = wl[nf];
      acc[nf] = __builtin_amdgcn_mfma_f32_16x16x32_f16(ah.h, bh.h, acc[nf], 0, 0, 0);
      acc[nf] = __builtin_amdgcn_mfma_f32_16x16x32_f16(al.h, bh.h, acc[nf], 0, 0, 0);
      acc[nf] = __builtin_amdgcn_mfma_f32_16x16x32_f16(ah.h, bl.h, acc[nf], 0, 0, 0);
    }
    // Prefetch next W fragments (L2-hot; used after next conversion block).
    if (ks + 1 < 16) {
#pragma unroll
      for (int nf = 0; nf < 4; ++nf) {
        wh[nf] = whb[(size_t)((ks + 1) * 16 + nf) * 64];
        wl[nf] = wlb[(size_t)((ks + 1) * 16 + nf) * 64];
      }
    }
  }

  // ---- fused e-dot epilogue ----
  // C-frag: lane holds rows (l>>4)*4+q (q=0..3), col l&15, per nf col-frag.
  float asv[4], adv[4];
#pragma unroll
  for (int nf = 0; nf < 4; ++nf) {
    const int c = ng * 64 + nf * 16 + lo16;
    asv[nf] = a[c];
    adv[nf] = a[F_OUT + c];
  }
#pragma unroll
  for (int q = 0; q < 4; ++q) {
    float s1 = acc[0][q] * asv[0] + acc[1][q] * asv[1] + acc[2][q] * asv[2] +
               acc[3][q] * asv[3];
    float s2 = acc[0][q] * adv[0] + acc[1][q] * adv[1] + acc[2][q] * adv[2] +
               acc[3][q] * adv[3];
#pragma unroll
    for (int o = 1; o < 16; o <<= 1) {
      s1 += __shfl_xor(s1, o);
      s2 += __shfl_xor(s2, o);
    }
    if (lo16 == 0) {
      const int rl = mg * 16 + hi4 * 4 + q;
      eip[ng][rl] = s1;
      ejp[ng][rl] = s2;
    }
  }

  // hpack scatter stores (layout unchanged from r5/r6 -> k_pv untouched).
#pragma unroll
  for (int nf = 0; nf < 4; ++nf) {
#pragma unroll
    for (int q = 0; q < 4; ++q) {
      const int row = r0 + mg * 16 + hi4 * 4 + q;
      const int col = ng * 64 + nf * 16 + lo16;
      const size_t idx =
          (((size_t)(row >> 5) * 16 + (col >> 4)) * 64 + (col & 15) +
           16 * ((row >> 3) & 3)) * 8 + (row & 7);
      const _Float16 hv = (_Float16)acc[nf][q];
      hpack[idx] = *(const unsigned short*)&hv;
    }
  }

  __syncthreads();
  if (tid < 32) {
    const float s1 = eip[0][tid] + eip[1][tid] + eip[2][tid] + eip[3][tid];
    const float s2 = ejp[0][tid] + ejp[1][tid] + ejp[2][tid] + ejp[3][tid];
    const int row = r0 + tid;
    EI[row] = s1 * LOG2E;
    const float e2 = s2 * LOG2E;
    EJ[row] = e2;
    emx[tid] = e2;
  }
  __syncthreads();
  if (tid == 0) {
    float m = emx[0];
#pragma unroll
    for (int i = 1; i < 32; ++i) m = fmaxf(m, emx[i]);
    unsigned b = __float_as_uint(m);
    unsigned u = (b & 0x80000000u) ? ~b : (b | 0x80000000u);
    atomicMax(emax_u, u);
  }
}

// ---------------------------------------------------------------------------
// k_pv (reverted to the proven r7 structure, 190.7us baseline): fused
// masked-softmax(P) @ h with 16x16x32 f16 MFMA. 64 rows x 256 cols per block;
// 64-wide j-tiles; raw s_barrier pipeline; depth-2 adj register prefetch.
// adj loads + npart/dpart stores NON-TEMPORAL so the streaming adj (268 MB)
// stops evicting the 4 MB hpack from each XCD L2.
// ---------------------------------------------------------------------------
__global__ __launch_bounds__(512, 4) void k_pv(const int* __restrict__ adj,
                                               const uint4* __restrict__ hp4,
                                               const float* __restrict__ EI,
                                               const float* __restrict__ EJ,
                                               const unsigned* __restrict__ emax_u,
                                               float* __restrict__ npart,
                                               float* __restrict__ dpart,
                                               int ntiles) {
  __shared__ __align__(16) uint4 ps4[8 * 64];   // 8 KB P tile (A-fragment layout)
  __shared__ float ejhi[2048], ejlo[2048];      // split's EJ, 0.2*EJ
  __shared__ float A1[64], A2[64], den[64];
  const int rowbase = blockIdx.x * 64;
  const int split   = blockIdx.y;
  const int jt0     = split * ntiles;
  const int tid     = threadIdx.x;
  const int wid  = tid >> 6, lane = tid & 63;
  const int lo   = lane & 15, hi = lane >> 4;

  float EMAX;
  {
    const unsigned u = *emax_u;
    EMAX = (u & 0x80000000u) ? __uint_as_float(u & 0x7fffffffu) : __uint_as_float(~u);
  }
  if (tid < 64) {
    const float e  = EI[rowbase + tid];
    const float s  = e + EMAX;
    const float mi = fmaxf(s, 0.2f * s);
    A1[tid] = e - mi;
    A2[tid] = 0.2f * e - mi;
    den[tid] = 0.f;
  }
  const bool uselds = (ntiles <= 32);
  if (uselds) {
    int eidx = jt0 * 64 + tid * 4;              // clamp guard (no-op at nsplit=4)
    if (eidx > N_NODES - 4) eidx = N_NODES - 4;
    const float4 ev = *(const float4*)&EJ[eidx];
    *(float4*)&ejhi[tid * 4] = ev;
    float4 el = {0.2f * ev.x, 0.2f * ev.y, 0.2f * ev.z, 0.2f * ev.w};
    *(float4*)&ejlo[tid * 4] = el;
  }
  __syncthreads();

  // P-writer role: slot wid = ksw*4 + msub.
  const int msub = wid & 3, ksw = wid >> 2;
  const int row_p = msub * 16 + lo;
  const int jloc  = ksw * 32 + hi * 8;
  const float a1r = A1[row_p], a2r = A2[row_p];
  const int*   adjp = adj + (size_t)(rowbase + row_p) * N_NODES + jt0 * 64 + jloc;
  const float* ejg  = EJ + jt0 * 64 + jloc;
  // MFMA-reader role: wave (mg,ng) owns rows [mg*32,+32) x cols [ng*64,+64).
  const int mg = wid >> 2, ng = wid & 3;
  const uint4* hb = hp4 + (ng * 4) * 64 + lane;

  f32x4 acc[2][4] = {};
  float dacc = 0.f;

  i32x4 cur0 = __builtin_nontemporal_load((const i32x4*)(adjp));
  i32x4 cur1 = __builtin_nontemporal_load((const i32x4*)(adjp + 4));
  i32x4 nxt0 = {0, 0, 0, 0}, nxt1 = {0, 0, 0, 0};
  if (ntiles > 1) {
    nxt0 = __builtin_nontemporal_load((const i32x4*)(adjp + 64));
    nxt1 = __builtin_nontemporal_load((const i32x4*)(adjp + 68));
  }

  for (int jt = 0; jt < ntiles; ++jt) {
    const int tb = (jt0 + jt) * 2048;  // uint4 offset of this tile's first k-block
    // B fragments for this tile (L2-hot with nt-adj protecting L2).
    const uint4 b00 = hb[tb + 0 * 1024 + 0 * 64];
    const uint4 b01 = hb[tb + 0 * 1024 + 1 * 64];
    const uint4 b02 = hb[tb + 0 * 1024 + 2 * 64];
    const uint4 b03 = hb[tb + 0 * 1024 + 3 * 64];
    const uint4 b10 = hb[tb + 1 * 1024 + 0 * 64];
    const uint4 b11 = hb[tb + 1 * 1024 + 1 * 64];
    const uint4 b12 = hb[tb + 1 * 1024 + 2 * 64];
    const uint4 b13 = hb[tb + 1 * 1024 + 3 * 64];

    // P compute: 8 values/thread.
    float eh[8], el[8];
    if (uselds) {
      const float4 h0 = *(const float4*)&ejhi[jt * 64 + jloc];
      const float4 h1 = *(const float4*)&ejhi[jt * 64 + jloc + 4];
      const float4 l0 = *(const float4*)&ejlo[jt * 64 + jloc];
      const float4 l1 = *(const float4*)&ejlo[jt * 64 + jloc + 4];
      eh[0]=h0.x; eh[1]=h0.y; eh[2]=h0.z; eh[3]=h0.w;
      eh[4]=h1.x; eh[5]=h1.y; eh[6]=h1.z; eh[7]=h1.w;
      el[0]=l0.x; el[1]=l0.y; el[2]=l0.z; el[3]=l0.w;
      el[4]=l1.x; el[5]=l1.y; el[6]=l1.z; el[7]=l1.w;
    } else {
      const float4 e0 = *(const float4*)(ejg + jt * 64);
      const float4 e1 = *(const float4*)(ejg + jt * 64 + 4);
      eh[0]=e0.x; eh[1]=e0.y; eh[2]=e0.z; eh[3]=e0.w;
      eh[4]=e1.x; eh[5]=e1.y; eh[6]=e1.z; eh[7]=e1.w;
#pragma unroll
      for (int j = 0; j < 8; ++j) el[j] = 0.2f * eh[j];
    }
    const int am[8] = {cur0.x, cur0.y, cur0.z, cur0.w, cur1.x, cur1.y, cur1.z, cur1.w};
    float ph[8];
#pragma unroll
    for (int j = 0; j < 8; ++j) {
      const float s = fmaxf(eh[j] + a1r, el[j] + a2r);
      const float p = __builtin_amdgcn_exp2f(s);
      ph[j] = (am[j] > 0) ? p : 0.f;
    }
    dacc += ((ph[0] + ph[1]) + (ph[2] + ph[3])) + ((ph[4] + ph[5]) + (ph[6] + ph[7]));
    H2U q0, q1, q2, q3;
    q0.h = __builtin_amdgcn_cvt_pkrtz(ph[0], ph[1]);
    q1.h = __builtin_amdgcn_cvt_pkrtz(ph[2], ph[3]);
    q2.h = __builtin_amdgcn_cvt_pkrtz(ph[4], ph[5]);
    q3.h = __builtin_amdgcn_cvt_pkrtz(ph[6], ph[7]);
    uint4 pk = {q0.u, q1.u, q2.u, q3.u};

    asm volatile("" ::: "memory");
    __builtin_amdgcn_s_barrier();        // all waves done reading ps4 (prev tile)
    asm volatile("" ::: "memory");
    ps4[wid * 64 + lane] = pk;
    // rotate prefetch regs; issue depth-2 adj prefetch (stays in flight).
    cur0 = nxt0; cur1 = nxt1;
    if (jt + 2 < ntiles) {
      const int* ap = adjp + (jt + 2) * 64;
      nxt0 = __builtin_nontemporal_load((const i32x4*)ap);
      nxt1 = __builtin_nontemporal_load((const i32x4*)(ap + 4));
    }
    asm volatile("s_waitcnt lgkmcnt(0)" ::: "memory");  // my ds_write visible
    __builtin_amdgcn_s_barrier();        // P tile ready
    asm volatile("" ::: "memory");

    H8U4 a00, a01, a10, a11;
    a00.u = ps4[(0 * 4 + mg * 2 + 0) * 64 + lane];
    a10.u = ps4[(0 * 4 + mg * 2 + 1) * 64 + lane];
    a01.u = ps4[(1 * 4 + mg * 2 + 0) * 64 + lane];
    a11.u = ps4[(1 * 4 + mg * 2 + 1) * 64 + lane];
    H8U4 b;
    __builtin_amdgcn_s_setprio(1);
    b.u = b00;
    acc[0][0] = __builtin_amdgcn_mfma_f32_16x16x32_f16(a00.h, b.h, acc[0][0], 0, 0, 0);
    acc[1][0] = __builtin_amdgcn_mfma_f32_16x16x32_f16(a10.h, b.h, acc[1][0], 0, 0, 0);
    b.u = b01;
    acc[0][1] = __builtin_amdgcn_mfma_f32_16x16x32_f16(a00.h, b.h, acc[0][1], 0, 0, 0);
    acc[1][1] = __builtin_amdgcn_mfma_f32_16x16x32_f16(a10.h, b.h, acc[1][1], 0, 0, 0);
    b.u = b02;
    acc[0][2] = __builtin_amdgcn_mfma_f32_16x16x32_f16(a00.h, b.h, acc[0][2], 0, 0, 0);
    acc[1][2] = __builtin_amdgcn_mfma_f32_16x16x32_f16(a10.h, b.h, acc[1][2], 0, 0, 0);
    b.u = b03;
    acc[0][3] = __builtin_amdgcn_mfma_f32_16x16x32_f16(a00.h, b.h, acc[0][3], 0, 0, 0);
    acc[1][3] = __builtin_amdgcn_mfma_f32_16x16x32_f16(a10.h, b.h, acc[1][3], 0, 0, 0);
    b.u = b10;
    acc[0][0] = __builtin_amdgcn_mfma_f32_16x16x32_f16(a01.h, b.h, acc[0][0], 0, 0, 0);
    acc[1][0] = __builtin_amdgcn_mfma_f32_16x16x32_f16(a11.h, b.h, acc[1][0], 0, 0, 0);
    b.u = b11;
    acc[0][1] = __builtin_amdgcn_mfma_f32_16x16x32_f16(a01.h, b.h, acc[0][1], 0, 0, 0);
    acc[1][1] = __builtin_amdgcn_mfma_f32_16x16x32_f16(a11.h, b.h, acc[1][1], 0, 0, 0);
    b.u = b12;
    acc[0][2] = __builtin_amdgcn_mfma_f32_16x16x32_f16(a01.h, b.h, acc[0][2], 0, 0, 0);
    acc[1][2] = __builtin_amdgcn_mfma_f32_16x16x32_f16(a11.h, b.h, acc[1][2], 0, 0, 0);
    b.u = b13;
    acc[0][3] = __builtin_amdgcn_mfma_f32_16x16x32_f16(a01.h, b.h, acc[0][3], 0, 0, 0);
    acc[1][3] = __builtin_amdgcn_mfma_f32_16x16x32_f16(a11.h, b.h, acc[1][3], 0, 0, 0);
    __builtin_amdgcn_s_setprio(0);
  }

  atomicAdd(&den[row_p], dacc);
  __syncthreads();

  float* npb = npart + (size_t)split * N_NODES * F_OUT;
#pragma unroll
  for (int mi_ = 0; mi_ < 2; ++mi_) {
    const int rb = rowbase + (mg * 2 + mi_) * 16 + hi * 4;
#pragma unroll
    for (int nf = 0; nf < 4; ++nf) {
      const int col = ng * 64 + nf * 16 + lo;
#pragma unroll
      for (int r2 = 0; r2 < 4; ++r2)
        __builtin_nontemporal_store(acc[mi_][nf][r2],
                                    &npb[(size_t)(rb + r2) * F_OUT + col]);
    }
  }
  if (tid < 64)
    __builtin_nontemporal_store(den[tid],
                                &dpart[(size_t)split * N_NODES + rowbase + tid]);
}

// ---------------------------------------------------------------------------
// k_fin: combine splits, divide by denom, ELU, write output.
// ---------------------------------------------------------------------------
__global__ __launch_bounds__(256) void k_fin(const float* __restrict__ npart,
                                             const float* __restrict__ dpart,
                                             float* __restrict__ out,
                                             int nsplit) {
  const int gid = blockIdx.x * 256 + threadIdx.x;
  const int row = gid >> 6;
  const int c4  = (gid & 63) << 2;
  f32x4 s = {0.f, 0.f, 0.f, 0.f};
  float d = 0.f;
  for (int sp = 0; sp < nsplit; ++sp) {
    const f32x4 v = __builtin_nontemporal_load(
        (const f32x4*)(npart + ((size_t)sp * N_NODES + row) * F_OUT + c4));
    s += v;
    d += dpart[(size_t)sp * N_NODES + row];
  }
  const float inv = 1.f / d;
  float o[4] = {s.x * inv, s.y * inv, s.z * inv, s.w * inv};
#pragma unroll
  for (int i = 0; i < 4; ++i) o[i] = (o[i] > 0.f) ? o[i] : expm1f(o[i]);
  float4 ov = {o[0], o[1], o[2], o[3]};
  *(float4*)(out + (size_t)row * F_OUT + c4) = ov;
}

// ---------------------------------------------------------------------------
extern "C" void kernel_launch(void* const* d_in, const int* in_sizes, int n_in,
                              void* d_out, int out_size, void* d_ws, size_t ws_size,
                              hipStream_t stream) {
  const float* x   = (const float*)d_in[0];
  const int*   adj = (const int*)d_in[1];
  const float* W   = (const float*)d_in[2];
  const float* a   = (const float*)d_in[3];
  float* out = (float*)d_out;
  char*  ws  = (char*)d_ws;

  unsigned short* hpack = (unsigned short*)ws;  // 4 MB, B-fragment layout
  size_t off = (size_t)4 * 1024 * 1024;
  float* EI = (float*)(ws + off); off += (size_t)N_NODES * 4;
  float* EJ = (float*)(ws + off); off += (size_t)N_NODES * 4;
  unsigned* emax_u = (unsigned*)(ws + off); off += 256;
  float* dpart = (float*)(ws + off); off += (size_t)8 * N_NODES * 4;
  unsigned short* wph = (unsigned short*)(ws + off); off += (size_t)F_IN * F_OUT * 2;
  unsigned short* wpl = (unsigned short*)(ws + off); off += (size_t)F_IN * F_OUT * 2;
  float* npart = (float*)(ws + off);

  int nsplit = 4;   // 512 blocks: all co-resident in one dispatch round (r6 lesson)
  while (nsplit > 1 && off + (size_t)nsplit * N_NODES * F_OUT * 4 > ws_size) nsplit >>= 1;

  k_prep<<<dim3((F_IN * F_OUT) / 256), dim3(256), 0, stream>>>(W, wph, wpl, emax_u);
  k_hgemm<<<dim3(N_NODES / 32), dim3(512), 0, stream>>>(
      x, (const uint4*)wph, (const uint4*)wpl, a, hpack, EI, EJ, emax_u);
  k_pv<<<dim3(128, nsplit), dim3(512), 0, stream>>>(adj, (const uint4*)hpack, EI, EJ,
                                                    emax_u, npart, dpart, 128 / nsplit);
  k_fin<<<dim3(N_NODES * 64 / 256), dim3(256), 0, stream>>>(npart, dpart, out, nsplit);
}